// Round 1
// baseline (1157.456 us; speedup 1.0000x reference)
//
#include <hip/hip_runtime.h>

#define LN_EPS 1e-5f

// Problem constants: N=2048, DIM_IN=256, DIM_V=256, NK=49, H=64, DIM_Q=16384
// q:    [2048][32768]  = x @ Wq^T + b          (ws, fp32, 268 MB)
// flat: [2048][12544]  = relu(ln1(t2))         (ws, fp32, 103 MB)
// wpart:[16][2048][256] split-K partials       (reuses q region)

// ---------------------------------------------------------------------------
// K1: q[2048][32768] = x[2048][256] @ Wq[32768][256]^T + Wqb
// 128x128 tile, BK=32, 256 threads, 8x8 per thread, fp32 VALU.
// ---------------------------------------------------------------------------
__global__ __launch_bounds__(256, 4) void k1_gemm_q(
    const float* __restrict__ x, const float* __restrict__ Wq,
    const float* __restrict__ Wqb, float* __restrict__ q)
{
    __shared__ __align__(16) float As[32][132];   // A^T tile, padded stride
    __shared__ __align__(16) float Bs[32][132];   // B^T tile
    const int tid = threadIdx.x;
    const int m0 = blockIdx.y << 7;
    const int j0 = blockIdx.x << 7;
    const int tx = tid & 15;
    const int ty = tid >> 4;

    float acc[8][8];
#pragma unroll
    for (int r = 0; r < 8; ++r)
#pragma unroll
        for (int c = 0; c < 8; ++c) acc[r][c] = 0.f;

    for (int k0 = 0; k0 < 256; k0 += 32) {
#pragma unroll
        for (int i = 0; i < 4; ++i) {
            const int f4 = tid + (i << 8);        // 0..1023
            const int row = f4 >> 3;              // 0..127
            const int kq = (f4 & 7) << 2;         // 0,4,...,28
            const float4 a = *(const float4*)(x + (m0 + row) * 256 + k0 + kq);
            As[kq + 0][row] = a.x; As[kq + 1][row] = a.y;
            As[kq + 2][row] = a.z; As[kq + 3][row] = a.w;
            const float4 b = *(const float4*)(Wq + (size_t)(j0 + row) * 256 + k0 + kq);
            Bs[kq + 0][row] = b.x; Bs[kq + 1][row] = b.y;
            Bs[kq + 2][row] = b.z; Bs[kq + 3][row] = b.w;
        }
        __syncthreads();
#pragma unroll 8
        for (int kk = 0; kk < 32; ++kk) {
            float a[8], b[8];
            *(float4*)&a[0] = *(const float4*)&As[kk][ty << 3];
            *(float4*)&a[4] = *(const float4*)&As[kk][(ty << 3) + 4];
            *(float4*)&b[0] = *(const float4*)&Bs[kk][tx << 3];
            *(float4*)&b[4] = *(const float4*)&Bs[kk][(tx << 3) + 4];
#pragma unroll
            for (int r = 0; r < 8; ++r)
#pragma unroll
                for (int c = 0; c < 8; ++c)
                    acc[r][c] = fmaf(a[r], b[c], acc[r][c]);
        }
        __syncthreads();
    }

    const float4 b0 = *(const float4*)(Wqb + j0 + (tx << 3));
    const float4 b1 = *(const float4*)(Wqb + j0 + (tx << 3) + 4);
#pragma unroll
    for (int r = 0; r < 8; ++r) {
        const int m = m0 + (ty << 3) + r;
        float* qp = q + (size_t)m * 32768 + j0 + (tx << 3);
        float4 o0, o1;
        o0.x = acc[r][0] + b0.x; o0.y = acc[r][1] + b0.y;
        o0.z = acc[r][2] + b0.z; o0.w = acc[r][3] + b0.w;
        o1.x = acc[r][4] + b1.x; o1.y = acc[r][5] + b1.y;
        o1.z = acc[r][6] + b1.z; o1.w = acc[r][7] + b1.w;
        *(float4*)qp = o0;
        *(float4*)(qp + 4) = o1;
    }
}

// ---------------------------------------------------------------------------
// K2: per-sample dynamic conv. 1 workgroup per sample, 256 threads.
//   phase A: t1[49][64]  = vt[49][256] @ p1[256][64];  ln0(h)+relu
//   phase B: t2[49][256] = th[49][64]  @ p2[64][256];  ln1(v)+relu -> flat
// LDS: sm0 = vt/t2 (stride 260, 49 rows), sm1 = p1/p2 (16384), smt = th (stride 68)
// ---------------------------------------------------------------------------
__global__ __launch_bounds__(256, 1) void k2_dynconv(
    const float* __restrict__ v, const float* __restrict__ q,
    const float* __restrict__ ln0g, const float* __restrict__ ln0b,
    const float* __restrict__ ln1g, const float* __restrict__ ln1b,
    float* __restrict__ flat)
{
    __shared__ __align__(16) float sm[32456];   // 129.8 KB
    float* const sm0 = sm;                      // 49*260 = 12740
    float* const sm1 = sm + 12740;              // 16384
    float* const smt = sm + 29124;              // 49*68 = 3332

    const int n = blockIdx.x;
    const int tid = threadIdx.x;
    const int lane = tid & 63;
    const int wid = tid >> 6;
    const float* vrow = v + (size_t)n * 12544;
    const float* qrow = q + (size_t)n * 32768;

    // stage vt (transposed v[n]) and p1 (= q[n][0:16384])
    for (int i = tid; i < 12544; i += 256) {
        const int dv = i / 49;
        const int k = i - dv * 49;
        sm0[k * 260 + dv] = vrow[i];
    }
    for (int i = tid << 2; i < 16384; i += 1024)
        *(float4*)&sm1[i] = *(const float4*)&qrow[i];
    __syncthreads();

    // ---- phase A: 4k x 4h tiles (13 x 16 = 208 active threads), dv-blocked x4
    {
        const int ktA = tid >> 4;
        const int hA = (tid & 15) << 2;
        if (ktA < 13) {
            const int kb = ktA << 2;
            int aoff[4];
#pragma unroll
            for (int r = 0; r < 4; ++r) {
                const int k = kb + r;
                aoff[r] = (k < 49 ? k : 48) * 260;   // clamp: rows 49..51 recompute row 48
            }
            float acc[4][4];
#pragma unroll
            for (int r = 0; r < 4; ++r)
#pragma unroll
                for (int c = 0; c < 4; ++c) acc[r][c] = 0.f;

#pragma unroll 2
            for (int dv = 0; dv < 256; dv += 4) {
                float4 av[4], bv[4];
#pragma unroll
                for (int r = 0; r < 4; ++r)
                    av[r] = *(const float4*)&sm0[aoff[r] + dv];
#pragma unroll
                for (int i = 0; i < 4; ++i)
                    bv[i] = *(const float4*)&sm1[(dv + i) * 64 + hA];
                const float* ap = (const float*)av;
                const float* bp = (const float*)bv;
#pragma unroll
                for (int r = 0; r < 4; ++r)
#pragma unroll
                    for (int i = 0; i < 4; ++i) {
                        const float a = ap[(r << 2) + i];
#pragma unroll
                        for (int c = 0; c < 4; ++c)
                            acc[r][c] = fmaf(a, bp[(i << 2) + c], acc[r][c]);
                    }
            }
#pragma unroll
            for (int r = 0; r < 4; ++r) {
                const int k = kb + r;
                if (k < 49) {
#pragma unroll
                    for (int c = 0; c < 4; ++c)
                        smt[k * 68 + hA + c] = acc[r][c];
                }
            }
        }
    }
    __syncthreads();

    // stage p2 (= q[n][16384:32768]) over p1's LDS; then LN0 while loads drain
    for (int i = tid << 2; i < 16384; i += 1024)
        *(float4*)&sm1[i] = *(const float4*)&qrow[16384 + i];

    {   // LN0 + relu over h (64), wave per row
        const float g = ln0g[lane];
        const float b = ln0b[lane];
        for (int k = wid; k < 49; k += 4) {
            const float val = smt[k * 68 + lane];
            float s1 = val, s2 = val * val;
#pragma unroll
            for (int off = 32; off > 0; off >>= 1) {
                s1 += __shfl_xor(s1, off);
                s2 += __shfl_xor(s2, off);
            }
            const float m = s1 * (1.f / 64.f);
            const float var = s2 * (1.f / 64.f) - m * m;
            const float rr = rsqrtf(var + LN_EPS);
            smt[k * 68 + lane] = fmaxf((val - m) * rr * g + b, 0.f);
        }
    }
    __syncthreads();

    // ---- phase B: 8k x 8j tiles (7 x 32 = 224 active threads), h-blocked x4
    if (tid < 224) {
        const int ktB = tid >> 5;
        const int jB = (tid & 31) << 3;
        int roff[8];
#pragma unroll
        for (int r = 0; r < 8; ++r) {
            const int k = (ktB << 3) + r;
            roff[r] = (k < 49 ? k : 48) * 68;
        }
        float acc[8][8];
#pragma unroll
        for (int r = 0; r < 8; ++r)
#pragma unroll
            for (int c = 0; c < 8; ++c) acc[r][c] = 0.f;

        for (int h = 0; h < 64; h += 4) {
            float4 av[8];
#pragma unroll
            for (int r = 0; r < 8; ++r)
                av[r] = *(const float4*)&smt[roff[r] + h];
            float4 bv[8];
#pragma unroll
            for (int i = 0; i < 4; ++i) {
                bv[i * 2 + 0] = *(const float4*)&sm1[(h + i) * 256 + jB];
                bv[i * 2 + 1] = *(const float4*)&sm1[(h + i) * 256 + jB + 4];
            }
            const float* ap = (const float*)av;
            const float* bp = (const float*)bv;
#pragma unroll
            for (int r = 0; r < 8; ++r)
#pragma unroll
                for (int i = 0; i < 4; ++i) {
                    const float a = ap[(r << 2) + i];
#pragma unroll
                    for (int c = 0; c < 8; ++c)
                        acc[r][c] = fmaf(a, bp[(i << 3) + c], acc[r][c]);
                }
        }
#pragma unroll
        for (int r = 0; r < 8; ++r) {
            const int k = (ktB << 3) + r;
            if (k < 49) {
                float4 o0, o1;
                o0.x = acc[r][0]; o0.y = acc[r][1]; o0.z = acc[r][2]; o0.w = acc[r][3];
                o1.x = acc[r][4]; o1.y = acc[r][5]; o1.z = acc[r][6]; o1.w = acc[r][7];
                *(float4*)&sm0[k * 260 + jB] = o0;
                *(float4*)&sm0[k * 260 + jB + 4] = o1;
            }
        }
    }
    __syncthreads();

    {   // LN1 + relu over j (256), wave per row -> flat
        float* frow = flat + (size_t)n * 12544;
        const int j4 = lane << 2;
        const float4 g4 = *(const float4*)&ln1g[j4];
        const float4 b4 = *(const float4*)&ln1b[j4];
        for (int k = wid; k < 49; k += 4) {
            const float4 val = *(const float4*)&sm0[k * 260 + j4];
            float s1 = val.x + val.y + val.z + val.w;
            float s2 = val.x*val.x + val.y*val.y + val.z*val.z + val.w*val.w;
#pragma unroll
            for (int off = 32; off > 0; off >>= 1) {
                s1 += __shfl_xor(s1, off);
                s2 += __shfl_xor(s2, off);
            }
            const float m = s1 * (1.f / 256.f);
            const float var = s2 * (1.f / 256.f) - m * m;
            const float rr = rsqrtf(var + LN_EPS);
            float4 o;
            o.x = fmaxf((val.x - m) * rr * g4.x + b4.x, 0.f);
            o.y = fmaxf((val.y - m) * rr * g4.y + b4.y, 0.f);
            o.z = fmaxf((val.z - m) * rr * g4.z + b4.z, 0.f);
            o.w = fmaxf((val.w - m) * rr * g4.w + b4.w, 0.f);
            *(float4*)&frow[k * 256 + j4] = o;
        }
    }
}

// ---------------------------------------------------------------------------
// K3: wpart[s][2048][256] partials of flat[2048][12544] @ Wv[256][12544]^T
// 128x128 tile, BK=16, split-K = 16 (784 K each), 8x8 per thread.
// ---------------------------------------------------------------------------
__global__ __launch_bounds__(256, 2) void k3_gemm_w(
    const float* __restrict__ flat, const float* __restrict__ Wv,
    float* __restrict__ wpart)
{
    __shared__ __align__(16) float As[16][132];
    __shared__ __align__(16) float Bs[16][132];
    const int tid = threadIdx.x;
    const int j0 = blockIdx.x << 7;      // 0,128
    const int m0 = blockIdx.y << 7;
    const int s = blockIdx.z;            // 0..15
    const int ksb = s * 784;
    const int tx = tid & 15;
    const int ty = tid >> 4;

    float acc[8][8];
#pragma unroll
    for (int r = 0; r < 8; ++r)
#pragma unroll
        for (int c = 0; c < 8; ++c) acc[r][c] = 0.f;

    for (int kc = 0; kc < 784; kc += 16) {
#pragma unroll
        for (int i = 0; i < 2; ++i) {
            const int f4 = tid + (i << 8);       // 0..511
            const int row = f4 >> 2;             // 0..127
            const int kq = (f4 & 3) << 2;        // 0,4,8,12
            const int kg = ksb + kc + kq;
            const float4 a = *(const float4*)(flat + (size_t)(m0 + row) * 12544 + kg);
            As[kq + 0][row] = a.x; As[kq + 1][row] = a.y;
            As[kq + 2][row] = a.z; As[kq + 3][row] = a.w;
            const float4 b = *(const float4*)(Wv + (size_t)(j0 + row) * 12544 + kg);
            Bs[kq + 0][row] = b.x; Bs[kq + 1][row] = b.y;
            Bs[kq + 2][row] = b.z; Bs[kq + 3][row] = b.w;
        }
        __syncthreads();
#pragma unroll 8
        for (int kk = 0; kk < 16; ++kk) {
            float a[8], b[8];
            *(float4*)&a[0] = *(const float4*)&As[kk][ty << 3];
            *(float4*)&a[4] = *(const float4*)&As[kk][(ty << 3) + 4];
            *(float4*)&b[0] = *(const float4*)&Bs[kk][tx << 3];
            *(float4*)&b[4] = *(const float4*)&Bs[kk][(tx << 3) + 4];
#pragma unroll
            for (int r = 0; r < 8; ++r)
#pragma unroll
                for (int c = 0; c < 8; ++c)
                    acc[r][c] = fmaf(a[r], b[c], acc[r][c]);
        }
        __syncthreads();
    }

#pragma unroll
    for (int r = 0; r < 8; ++r) {
        const int m = m0 + (ty << 3) + r;
        float* wp = wpart + ((size_t)s * 2048 + m) * 256 + j0 + (tx << 3);
        const float4 o0 = make_float4(acc[r][0], acc[r][1], acc[r][2], acc[r][3]);
        const float4 o1 = make_float4(acc[r][4], acc[r][5], acc[r][6], acc[r][7]);
        *(float4*)wp = o0;
        *(float4*)(wp + 4) = o1;
    }
}

// ---------------------------------------------------------------------------
// K4: reduce 16 partials + Wv_b -> lnv+relu -> +x -> lnf -> out. Wave per row.
// ---------------------------------------------------------------------------
__global__ __launch_bounds__(256) void k4_final(
    const float* __restrict__ wpart, const float* __restrict__ x,
    const float* __restrict__ Wvb,
    const float* __restrict__ lnvg, const float* __restrict__ lnvb,
    const float* __restrict__ lnfg, const float* __restrict__ lnfb,
    float* __restrict__ out)
{
    const int n = (blockIdx.x << 2) + (threadIdx.x >> 6);
    const int lane = threadIdx.x & 63;
    const int j = lane << 2;

    float a0 = 0.f, a1 = 0.f, a2 = 0.f, a3 = 0.f;
#pragma unroll
    for (int s = 0; s < 16; ++s) {
        const float4 p = *(const float4*)&wpart[((size_t)s * 2048 + n) * 256 + j];
        a0 += p.x; a1 += p.y; a2 += p.z; a3 += p.w;
    }
    const float4 bb = *(const float4*)&Wvb[j];
    a0 += bb.x; a1 += bb.y; a2 += bb.z; a3 += bb.w;

    float s1 = a0 + a1 + a2 + a3;
    float s2 = a0*a0 + a1*a1 + a2*a2 + a3*a3;
#pragma unroll
    for (int off = 32; off > 0; off >>= 1) {
        s1 += __shfl_xor(s1, off);
        s2 += __shfl_xor(s2, off);
    }
    float m = s1 * (1.f / 256.f);
    float var = s2 * (1.f / 256.f) - m * m;
    float rr = rsqrtf(var + LN_EPS);
    const float4 g = *(const float4*)&lnvg[j];
    const float4 b = *(const float4*)&lnvb[j];
    const float w0 = fmaxf((a0 - m) * rr * g.x + b.x, 0.f);
    const float w1 = fmaxf((a1 - m) * rr * g.y + b.y, 0.f);
    const float w2 = fmaxf((a2 - m) * rr * g.z + b.z, 0.f);
    const float w3 = fmaxf((a3 - m) * rr * g.w + b.w, 0.f);

    const float4 xv = *(const float4*)&x[(size_t)n * 256 + j];
    const float t0 = xv.x + w0, t1 = xv.y + w1, t2 = xv.z + w2, t3 = xv.w + w3;
    s1 = t0 + t1 + t2 + t3;
    s2 = t0*t0 + t1*t1 + t2*t2 + t3*t3;
#pragma unroll
    for (int off = 32; off > 0; off >>= 1) {
        s1 += __shfl_xor(s1, off);
        s2 += __shfl_xor(s2, off);
    }
    m = s1 * (1.f / 256.f);
    var = s2 * (1.f / 256.f) - m * m;
    rr = rsqrtf(var + LN_EPS);
    const float4 gf = *(const float4*)&lnfg[j];
    const float4 bf = *(const float4*)&lnfb[j];
    float4 o;
    o.x = (t0 - m) * rr * gf.x + bf.x;
    o.y = (t1 - m) * rr * gf.y + bf.y;
    o.z = (t2 - m) * rr * gf.z + bf.z;
    o.w = (t3 - m) * rr * gf.w + bf.w;
    *(float4*)&out[(size_t)n * 256 + j] = o;
}

// ---------------------------------------------------------------------------
extern "C" void kernel_launch(void* const* d_in, const int* in_sizes, int n_in,
                              void* d_out, int out_size, void* d_ws, size_t ws_size,
                              hipStream_t stream)
{
    const float* x    = (const float*)d_in[0];
    const float* v    = (const float*)d_in[1];
    const float* Wq_w = (const float*)d_in[2];
    const float* Wq_b = (const float*)d_in[3];
    const float* ln0g = (const float*)d_in[4];
    const float* ln0b = (const float*)d_in[5];
    const float* ln1g = (const float*)d_in[6];
    const float* ln1b = (const float*)d_in[7];
    const float* Wv_w = (const float*)d_in[8];
    const float* Wv_b = (const float*)d_in[9];
    const float* lnvg = (const float*)d_in[10];
    const float* lnvb = (const float*)d_in[11];
    const float* lnfg = (const float*)d_in[12];
    const float* lnfb = (const float*)d_in[13];
    float* out = (float*)d_out;

    // ws layout: q [2048][32768] f32 (268,435,456 B) | flat [2048][12544] f32
    // wpart reuses the q region after K2 has consumed q (stream-serialized).
    if (ws_size < 371195904ull) return;  // loud failure: out stays poisoned
    char* ws = (char*)d_ws;
    float* q     = (float*)ws;
    float* flat  = (float*)(ws + 268435456u);
    float* wpart = q;

    k1_gemm_q<<<dim3(256, 16), 256, 0, stream>>>(x, Wq_w, Wq_b, q);
    k2_dynconv<<<2048, 256, 0, stream>>>(v, q, ln0g, ln0b, ln1g, ln1b, flat);
    k3_gemm_w<<<dim3(2, 16, 16), 256, 0, stream>>>(flat, Wv_w, wpart);
    k4_final<<<512, 256, 0, stream>>>(wpart, x, Wv_b, lnvg, lnvb, lnfg, lnfb, out);
}

// Round 6
// 973.181 us; speedup vs baseline: 1.1894x; 1.1894x over previous
//
#include <hip/hip_runtime.h>

#define LN_EPS 1e-5f

// Problem constants: N=2048, DIM_IN=256, DIM_V=256, VH=VW=7 (NK=49), H=64
//
// Pipeline:
//   k0_split : x -> xs_hi/xs_lo bf16 planes (trunc split)
//   gemm_sb3 : q[2048][32768] = x @ Wq^T + b   (split-bf16 3-term MFMA)
//   k2       : per-sample dynamic conv (fp32) -> flat hi/lo bf16 planes
//   gemm_sb3 : wpart[14][2048][256] = flat @ Wv^T partials (split-K=14)
//   k4       : reduce 14 partials + bias -> lnv+relu -> +x -> lnf -> out
//
// ws layout (byte offsets), total 371,195,904 (same as round 1):
//   [0, 268435456)          q fp32 [2048][32768]; reused as wpart after K2
//   [268435456, 371195904)  flat planes: hi ushort[2048][12544] @ +0,
//                                        lo @ +51380224
//   xs planes (2 MB) overlay the flat region during K0/K1 (dead by K2).

typedef __attribute__((ext_vector_type(8))) short short8;
typedef __attribute__((ext_vector_type(16))) float f32x16;

// ---------------------------------------------------------------------------
// K0: fp32 -> bf16 hi/lo planes (truncation split: exact a = hi + lo + O(2^-16))
// ---------------------------------------------------------------------------
__global__ __launch_bounds__(256) void k0_split(
    const float* __restrict__ in, ushort* __restrict__ hi,
    ushort* __restrict__ lo, int n4)
{
    const int i = blockIdx.x * 256 + threadIdx.x;
    if (i >= n4) return;
    const float4 f = ((const float4*)in)[i];
    const uint ux = __float_as_uint(f.x), uy = __float_as_uint(f.y);
    const uint uz = __float_as_uint(f.z), uw = __float_as_uint(f.w);
    ushort4 h, l;
    h.x = (ushort)(ux >> 16); h.y = (ushort)(uy >> 16);
    h.z = (ushort)(uz >> 16); h.w = (ushort)(uw >> 16);
    l.x = (ushort)(__float_as_uint(f.x - __uint_as_float(ux & 0xffff0000u)) >> 16);
    l.y = (ushort)(__float_as_uint(f.y - __uint_as_float(uy & 0xffff0000u)) >> 16);
    l.z = (ushort)(__float_as_uint(f.z - __uint_as_float(uz & 0xffff0000u)) >> 16);
    l.w = (ushort)(__float_as_uint(f.w - __uint_as_float(uw & 0xffff0000u)) >> 16);
    ((ushort4*)hi)[i] = h;
    ((ushort4*)lo)[i] = l;
}

// ---------------------------------------------------------------------------
// Split-bf16 3-term MFMA GEMM:  C[m][j] (+)= sum_k A[m][k]*B[j][k]
//   A: pre-split bf16 hi/lo planes (row-major, stride lda, k-contiguous)
//   B: fp32 row-major (stride ldb, k-contiguous), split in-kernel
// Tile 128x128, BK=64, 256 thr = 4 waves (2x2), wave = 2x2 frags of 32x32x16.
// LDS planes [128][64] bf16, XOR-swizzled (idx ^= (row&7)<<3 in ushorts).
// grid = (M/128, N/128, S); split s handles k in [s*kPerSplit, (s+1)*kPerSplit)
// ---------------------------------------------------------------------------
template<bool HAS_BIAS>
__global__ __launch_bounds__(256, 2) void gemm_sb3(
    const ushort* __restrict__ Ah, const ushort* __restrict__ Al,
    const float* __restrict__ B, const float* __restrict__ bias,
    float* __restrict__ C, int lda, int ldb, int ldc,
    size_t cSplitStride, int kPerSplit)
{
    __shared__ __align__(16) ushort sAh[8192];
    __shared__ __align__(16) ushort sAl[8192];
    __shared__ __align__(16) ushort sBh[8192];
    __shared__ __align__(16) ushort sBl[8192];

    const int tid = threadIdx.x;
    const int m0 = blockIdx.x << 7;
    const int j0 = blockIdx.y << 7;
    const int ks0 = blockIdx.z * kPerSplit;
    float* Cb = C + (size_t)blockIdx.z * cSplitStride;

    const int lane = tid & 63;
    const int wid = tid >> 6;
    const int wr = wid >> 1;             // wave row (0..1)
    const int wc = wid & 1;              // wave col (0..1)
    const int swz = (lane & 7) << 3;     // LDS xor-swizzle (ushort units)
    const int rA = (wr << 6) + (lane & 31);
    const int rB = (wc << 6) + (lane & 31);
    const int khalf = (lane >> 5) << 3;  // 0 or 8 (k-half of the fragment)

    f32x16 acc[2][2];
#pragma unroll
    for (int r = 0; r < 2; ++r)
#pragma unroll
        for (int c = 0; c < 2; ++c)
#pragma unroll
            for (int e = 0; e < 16; ++e) acc[r][c][e] = 0.f;

    for (int kg0 = 0; kg0 < kPerSplit; kg0 += 64) {
        const int kg = ks0 + kg0;

        // ---- issue all global loads first (latency overlaps prev compute)
        uint4 av[8];
#pragma unroll
        for (int p = 0; p < 2; ++p) {
            const ushort* src = p ? Al : Ah;
#pragma unroll
            for (int i = 0; i < 4; ++i) {
                const int id = tid + (i << 8);      // 0..1023
                const int row = id >> 3;            // 0..127
                const int c8 = (id & 7) << 3;       // 0..56
                av[p * 4 + i] = *(const uint4*)(src + (size_t)(m0 + row) * lda + kg + c8);
            }
        }
        float4 bv[8];
#pragma unroll
        for (int i = 0; i < 8; ++i) {
            const int id = tid + (i << 8);          // 0..2047
            const int row = id >> 4;                // 0..127
            const int c4 = (id & 15) << 2;          // 0..60
            bv[i] = *(const float4*)(B + (size_t)(j0 + row) * ldb + kg + c4);
        }

        if (kg0 > 0) __syncthreads();   // prev iter's readers done before overwrite

        // ---- A planes: straight bf16 copy into swizzled LDS
#pragma unroll
        for (int p = 0; p < 2; ++p) {
            ushort* dst = p ? sAl : sAh;
#pragma unroll
            for (int i = 0; i < 4; ++i) {
                const int id = tid + (i << 8);
                const int row = id >> 3;
                const int c8 = (id & 7) << 3;
                *(uint4*)&dst[((row << 6) + c8) ^ ((row & 7) << 3)] = av[p * 4 + i];
            }
        }
        // ---- B: trunc-split fp32 -> hi/lo bf16, write both planes
#pragma unroll
        for (int i = 0; i < 8; ++i) {
            const int id = tid + (i << 8);
            const int row = id >> 4;
            const int c4 = (id & 15) << 2;
            const uint ux = __float_as_uint(bv[i].x), uy = __float_as_uint(bv[i].y);
            const uint uz = __float_as_uint(bv[i].z), uw = __float_as_uint(bv[i].w);
            const float lx = bv[i].x - __uint_as_float(ux & 0xffff0000u);
            const float ly = bv[i].y - __uint_as_float(uy & 0xffff0000u);
            const float lz = bv[i].z - __uint_as_float(uz & 0xffff0000u);
            const float lw = bv[i].w - __uint_as_float(uw & 0xffff0000u);
            const uint h01 = (ux >> 16) | (uy & 0xffff0000u);
            const uint h23 = (uz >> 16) | (uw & 0xffff0000u);
            const uint l01 = (__float_as_uint(lx) >> 16) | (__float_as_uint(ly) & 0xffff0000u);
            const uint l23 = (__float_as_uint(lz) >> 16) | (__float_as_uint(lw) & 0xffff0000u);
            const int sidx = ((row << 6) + c4) ^ ((row & 7) << 3);
            *(uint2*)&sBh[sidx] = make_uint2(h01, h23);
            *(uint2*)&sBl[sidx] = make_uint2(l01, l23);
        }
        __syncthreads();

        // ---- MFMA: 4 k-steps of 16; 12 MFMAs per k-step (2x2 frags x 3 terms)
#pragma unroll
        for (int ks = 0; ks < 4; ++ks) {
            const int kf = (ks << 4) + khalf;
            const int ia0 = ((rA << 6) + kf) ^ swz;
            const int ia1 = (((rA + 32) << 6) + kf) ^ swz;
            const int ib0 = ((rB << 6) + kf) ^ swz;
            const int ib1 = (((rB + 32) << 6) + kf) ^ swz;
            const short8 a0h = *(const short8*)&sAh[ia0];
            const short8 a0l = *(const short8*)&sAl[ia0];
            const short8 a1h = *(const short8*)&sAh[ia1];
            const short8 a1l = *(const short8*)&sAl[ia1];
            const short8 b0h = *(const short8*)&sBh[ib0];
            const short8 b0l = *(const short8*)&sBl[ib0];
            const short8 b1h = *(const short8*)&sBh[ib1];
            const short8 b1l = *(const short8*)&sBl[ib1];

            acc[0][0] = __builtin_amdgcn_mfma_f32_32x32x16_bf16(a0h, b0h, acc[0][0], 0, 0, 0);
            acc[0][1] = __builtin_amdgcn_mfma_f32_32x32x16_bf16(a0h, b1h, acc[0][1], 0, 0, 0);
            acc[1][0] = __builtin_amdgcn_mfma_f32_32x32x16_bf16(a1h, b0h, acc[1][0], 0, 0, 0);
            acc[1][1] = __builtin_amdgcn_mfma_f32_32x32x16_bf16(a1h, b1h, acc[1][1], 0, 0, 0);
            acc[0][0] = __builtin_amdgcn_mfma_f32_32x32x16_bf16(a0h, b0l, acc[0][0], 0, 0, 0);
            acc[0][1] = __builtin_amdgcn_mfma_f32_32x32x16_bf16(a0h, b1l, acc[0][1], 0, 0, 0);
            acc[1][0] = __builtin_amdgcn_mfma_f32_32x32x16_bf16(a1h, b0l, acc[1][0], 0, 0, 0);
            acc[1][1] = __builtin_amdgcn_mfma_f32_32x32x16_bf16(a1h, b1l, acc[1][1], 0, 0, 0);
            acc[0][0] = __builtin_amdgcn_mfma_f32_32x32x16_bf16(a0l, b0h, acc[0][0], 0, 0, 0);
            acc[0][1] = __builtin_amdgcn_mfma_f32_32x32x16_bf16(a0l, b1h, acc[0][1], 0, 0, 0);
            acc[1][0] = __builtin_amdgcn_mfma_f32_32x32x16_bf16(a1l, b0h, acc[1][0], 0, 0, 0);
            acc[1][1] = __builtin_amdgcn_mfma_f32_32x32x16_bf16(a1l, b1h, acc[1][1], 0, 0, 0);
        }
    }

    // ---- epilogue: C/D layout (verified): col = lane&31, row = (reg&3)+8*(reg>>2)+4*(lane>>5)
#pragma unroll
    for (int rb = 0; rb < 2; ++rb)
#pragma unroll
        for (int cb = 0; cb < 2; ++cb) {
            const int col = j0 + (wc << 6) + (cb << 5) + (lane & 31);
            const float bvv = HAS_BIAS ? bias[col] : 0.0f;
            const int rbase = m0 + (wr << 6) + (rb << 5) + ((lane >> 5) << 2);
            float* cp = Cb + (size_t)rbase * ldc + col;
#pragma unroll
            for (int reg = 0; reg < 16; ++reg) {
                const int rr = (reg & 3) + ((reg >> 2) << 3);
                cp[(size_t)rr * ldc] = acc[rb][cb][reg] + bvv;
            }
        }
}

// ---------------------------------------------------------------------------
// K2: per-sample dynamic conv. 1 workgroup per sample, 256 threads (fp32).
//   phase A: t1[49][64]  = vt[49][256] @ p1[256][64];  ln0(h)+relu
//   phase B: t2[49][256] = th[49][64]  @ p2[64][256];  ln1(v)+relu -> flat planes
// ---------------------------------------------------------------------------
__global__ __launch_bounds__(256, 1) void k2_dynconv(
    const float* __restrict__ v, const float* __restrict__ q,
    const float* __restrict__ ln0g, const float* __restrict__ ln0b,
    const float* __restrict__ ln1g, const float* __restrict__ ln1b,
    ushort* __restrict__ fhi, ushort* __restrict__ flo)
{
    __shared__ __align__(16) float sm[32456];   // 129.8 KB
    float* const sm0 = sm;                      // 49*260 = 12740
    float* const sm1 = sm + 12740;              // 16384
    float* const smt = sm + 29124;              // 49*68 = 3332

    const int n = blockIdx.x;
    const int tid = threadIdx.x;
    const int lane = tid & 63;
    const int wid = tid >> 6;
    const float* vrow = v + (size_t)n * 12544;
    const float* qrow = q + (size_t)n * 32768;

    for (int i = tid; i < 12544; i += 256) {
        const int dv = i / 49;
        const int k = i - dv * 49;
        sm0[k * 260 + dv] = vrow[i];
    }
    for (int i = tid << 2; i < 16384; i += 1024)
        *(float4*)&sm1[i] = *(const float4*)&qrow[i];
    __syncthreads();

    // ---- phase A: 4k x 4h tiles (13 x 16 = 208 active threads)
    {
        const int ktA = tid >> 4;
        const int hA = (tid & 15) << 2;
        if (ktA < 13) {
            const int kb = ktA << 2;
            int aoff[4];
#pragma unroll
            for (int r = 0; r < 4; ++r) {
                const int k = kb + r;
                aoff[r] = (k < 49 ? k : 48) * 260;
            }
            float acc[4][4];
#pragma unroll
            for (int r = 0; r < 4; ++r)
#pragma unroll
                for (int c = 0; c < 4; ++c) acc[r][c] = 0.f;

#pragma unroll 2
            for (int dv = 0; dv < 256; dv += 4) {
                float4 av[4], bv[4];
#pragma unroll
                for (int r = 0; r < 4; ++r)
                    av[r] = *(const float4*)&sm0[aoff[r] + dv];
#pragma unroll
                for (int i = 0; i < 4; ++i)
                    bv[i] = *(const float4*)&sm1[(dv + i) * 64 + hA];
                const float* ap = (const float*)av;
                const float* bp = (const float*)bv;
#pragma unroll
                for (int r = 0; r < 4; ++r)
#pragma unroll
                    for (int i = 0; i < 4; ++i) {
                        const float a = ap[(r << 2) + i];
#pragma unroll
                        for (int c = 0; c < 4; ++c)
                            acc[r][c] = fmaf(a, bp[(i << 2) + c], acc[r][c]);
                    }
            }
#pragma unroll
            for (int r = 0; r < 4; ++r) {
                const int k = kb + r;
                if (k < 49) {
#pragma unroll
                    for (int c = 0; c < 4; ++c)
                        smt[k * 68 + hA + c] = acc[r][c];
                }
            }
        }
    }
    __syncthreads();

    for (int i = tid << 2; i < 16384; i += 1024)
        *(float4*)&sm1[i] = *(const float4*)&qrow[16384 + i];

    {   // LN0 + relu over h (64), wave per row
        const float g = ln0g[lane];
        const float b = ln0b[lane];
        for (int k = wid; k < 49; k += 4) {
            const float val = smt[k * 68 + lane];
            float s1 = val, s2 = val * val;
#pragma unroll
            for (int off = 32; off > 0; off >>= 1) {
                s1 += __shfl_xor(s1, off);
                s2 += __shfl_xor(s2, off);
            }
            const float m = s1 * (1.f / 64.f);
            const float var = s2 * (1.f / 64.f) - m * m;
            const float rr = rsqrtf(var + LN_EPS);
            smt[k * 68 + lane] = fmaxf((val - m) * rr * g + b, 0.f);
        }
    }
    __syncthreads();

    // ---- phase B: 8k x 8j tiles (7 x 32 = 224 active threads)
    if (tid < 224) {
        const int ktB = tid >> 5;
        const int jB = (tid & 31) << 3;
        int roff[8];
#pragma unroll
        for (int r = 0; r < 8; ++r) {
            const int k = (ktB << 3) + r;
            roff[r] = (k < 49 ? k : 48) * 68;
        }
        float acc[8][8];
#pragma unroll
        for (int r = 0; r < 8; ++r)
#pragma unroll
            for (int c = 0; c < 8; ++c) acc[r][c] = 0.f;

        for (int h = 0; h < 64; h += 4) {
            float4 av[8];
#pragma unroll
            for (int r = 0; r < 8; ++r)
                av[r] = *(const float4*)&smt[roff[r] + h];
            float4 bv[8];
#pragma unroll
            for (int i = 0; i < 4; ++i) {
                bv[i * 2 + 0] = *(const float4*)&sm1[(h + i) * 256 + jB];
                bv[i * 2 + 1] = *(const float4*)&sm1[(h + i) * 256 + jB + 4];
            }
            const float* ap = (const float*)av;
            const float* bp = (const float*)bv;
#pragma unroll
            for (int r = 0; r < 8; ++r)
#pragma unroll
                for (int i = 0; i < 4; ++i) {
                    const float a = ap[(r << 2) + i];
#pragma unroll
                    for (int c = 0; c < 8; ++c)
                        acc[r][c] = fmaf(a, bp[(i << 3) + c], acc[r][c]);
                }
        }
#pragma unroll
        for (int r = 0; r < 8; ++r) {
            const int k = (ktB << 3) + r;
            if (k < 49) {
                float4 o0, o1;
                o0.x = acc[r][0]; o0.y = acc[r][1]; o0.z = acc[r][2]; o0.w = acc[r][3];
                o1.x = acc[r][4]; o1.y = acc[r][5]; o1.z = acc[r][6]; o1.w = acc[r][7];
                *(float4*)&sm0[k * 260 + jB] = o0;
                *(float4*)&sm0[k * 260 + jB + 4] = o1;
            }
        }
    }
    __syncthreads();

    {   // LN1 + relu over j (256), wave per row -> flat hi/lo planes
        const int j4 = lane << 2;
        const float4 g4 = *(const float4*)&ln1g[j4];
        const float4 b4 = *(const float4*)&ln1b[j4];
        for (int k = wid; k < 49; k += 4) {
            const float4 val = *(const float4*)&sm0[k * 260 + j4];
            float s1 = val.x + val.y + val.z + val.w;
            float s2 = val.x*val.x + val.y*val.y + val.z*val.z + val.w*val.w;
#pragma unroll
            for (int off = 32; off > 0; off >>= 1) {
                s1 += __shfl_xor(s1, off);
                s2 += __shfl_xor(s2, off);
            }
            const float m = s1 * (1.f / 256.f);
            const float var = s2 * (1.f / 256.f) - m * m;
            const float rr = rsqrtf(var + LN_EPS);
            float o0 = fmaxf((val.x - m) * rr * g4.x + b4.x, 0.f);
            float o1 = fmaxf((val.y - m) * rr * g4.y + b4.y, 0.f);
            float o2 = fmaxf((val.z - m) * rr * g4.z + b4.z, 0.f);
            float o3 = fmaxf((val.w - m) * rr * g4.w + b4.w, 0.f);
            const uint u0 = __float_as_uint(o0), u1 = __float_as_uint(o1);
            const uint u2 = __float_as_uint(o2), u3 = __float_as_uint(o3);
            ushort4 h4, l4;
            h4.x = (ushort)(u0 >> 16); h4.y = (ushort)(u1 >> 16);
            h4.z = (ushort)(u2 >> 16); h4.w = (ushort)(u3 >> 16);
            l4.x = (ushort)(__float_as_uint(o0 - __uint_as_float(u0 & 0xffff0000u)) >> 16);
            l4.y = (ushort)(__float_as_uint(o1 - __uint_as_float(u1 & 0xffff0000u)) >> 16);
            l4.z = (ushort)(__float_as_uint(o2 - __uint_as_float(u2 & 0xffff0000u)) >> 16);
            l4.w = (ushort)(__float_as_uint(o3 - __uint_as_float(u3 & 0xffff0000u)) >> 16);
            const size_t fo = (size_t)n * 12544 + k * 256 + j4;
            *(ushort4*)&fhi[fo] = h4;
            *(ushort4*)&flo[fo] = l4;
        }
    }
}

// ---------------------------------------------------------------------------
// K4: reduce 14 split-K partials + Wv_b -> lnv+relu -> +x -> lnf -> out.
// ---------------------------------------------------------------------------
__global__ __launch_bounds__(256) void k4_final(
    const float* __restrict__ wpart, const float* __restrict__ x,
    const float* __restrict__ Wvb,
    const float* __restrict__ lnvg, const float* __restrict__ lnvb,
    const float* __restrict__ lnfg, const float* __restrict__ lnfb,
    float* __restrict__ out)
{
    const int n = (blockIdx.x << 2) + (threadIdx.x >> 6);
    const int lane = threadIdx.x & 63;
    const int j = lane << 2;

    float a0 = 0.f, a1 = 0.f, a2 = 0.f, a3 = 0.f;
#pragma unroll
    for (int s = 0; s < 14; ++s) {
        const float4 p = *(const float4*)&wpart[((size_t)s * 2048 + n) * 256 + j];
        a0 += p.x; a1 += p.y; a2 += p.z; a3 += p.w;
    }
    const float4 bb = *(const float4*)&Wvb[j];
    a0 += bb.x; a1 += bb.y; a2 += bb.z; a3 += bb.w;

    float s1 = a0 + a1 + a2 + a3;
    float s2 = a0*a0 + a1*a1 + a2*a2 + a3*a3;
#pragma unroll
    for (int off = 32; off > 0; off >>= 1) {
        s1 += __shfl_xor(s1, off);
        s2 += __shfl_xor(s2, off);
    }
    float m = s1 * (1.f / 256.f);
    float var = s2 * (1.f / 256.f) - m * m;
    float rr = rsqrtf(var + LN_EPS);
    const float4 g = *(const float4*)&lnvg[j];
    const float4 b = *(const float4*)&lnvb[j];
    const float w0 = fmaxf((a0 - m) * rr * g.x + b.x, 0.f);
    const float w1 = fmaxf((a1 - m) * rr * g.y + b.y, 0.f);
    const float w2 = fmaxf((a2 - m) * rr * g.z + b.z, 0.f);
    const float w3 = fmaxf((a3 - m) * rr * g.w + b.w, 0.f);

    const float4 xv = *(const float4*)&x[(size_t)n * 256 + j];
    const float t0 = xv.x + w0, t1 = xv.y + w1, t2 = xv.z + w2, t3 = xv.w + w3;
    s1 = t0 + t1 + t2 + t3;
    s2 = t0*t0 + t1*t1 + t2*t2 + t3*t3;
#pragma unroll
    for (int off = 32; off > 0; off >>= 1) {
        s1 += __shfl_xor(s1, off);
        s2 += __shfl_xor(s2, off);
    }
    m = s1 * (1.f / 256.f);
    var = s2 * (1.f / 256.f) - m * m;
    rr = rsqrtf(var + LN_EPS);
    const float4 gf = *(const float4*)&lnfg[j];
    const float4 bf = *(const float4*)&lnfb[j];
    float4 o;
    o.x = (t0 - m) * rr * gf.x + bf.x;
    o.y = (t1 - m) * rr * gf.y + bf.y;
    o.z = (t2 - m) * rr * gf.z + bf.z;
    o.w = (t3 - m) * rr * gf.w + bf.w;
    *(float4*)&out[(size_t)n * 256 + j] = o;
}

// ---------------------------------------------------------------------------
extern "C" void kernel_launch(void* const* d_in, const int* in_sizes, int n_in,
                              void* d_out, int out_size, void* d_ws, size_t ws_size,
                              hipStream_t stream)
{
    const float* x    = (const float*)d_in[0];
    const float* v    = (const float*)d_in[1];
    const float* Wq_w = (const float*)d_in[2];
    const float* Wq_b = (const float*)d_in[3];
    const float* ln0g = (const float*)d_in[4];
    const float* ln0b = (const float*)d_in[5];
    const float* ln1g = (const float*)d_in[6];
    const float* ln1b = (const float*)d_in[7];
    const float* Wv_w = (const float*)d_in[8];
    const float* Wv_b = (const float*)d_in[9];
    const float* lnvg = (const float*)d_in[10];
    const float* lnvb = (const float*)d_in[11];
    const float* lnfg = (const float*)d_in[12];
    const float* lnfb = (const float*)d_in[13];
    float* out = (float*)d_out;

    if (ws_size < 371195904ull) return;  // loud failure: out stays poisoned
    char* ws = (char*)d_ws;
    float* q        = (float*)ws;                          // [2048][32768] fp32
    ushort* flat_hi = (ushort*)(ws + 268435456u);          // [2048][12544] bf16
    ushort* flat_lo = (ushort*)(ws + 319815680u);
    ushort* xs_hi   = (ushort*)(ws + 268435456u);          // overlay (dead by K2)
    ushort* xs_lo   = xs_hi + 524288;
    float* wpart    = q;                                   // [14][2048][256] fp32

    // K0: split x into bf16 hi/lo planes (131072 float4 chunks)
    k0_split<<<512, 256, 0, stream>>>(x, xs_hi, xs_lo, 131072);

    // K1: q = x @ Wq^T + b   (M=2048, N=32768, K=256)
    gemm_sb3<true><<<dim3(16, 256, 1), 256, 0, stream>>>(
        xs_hi, xs_lo, Wq_w, Wq_b, q, 256, 256, 32768, 0, 256);

    // K2: dynamic conv, writes flat hi/lo planes
    k2_dynconv<<<2048, 256, 0, stream>>>(v, q, ln0g, ln0b, ln1g, ln1b,
                                         flat_hi, flat_lo);

    // K3: wpart[s] = flat @ Wv^T partials (M=2048, N=256, K=12544, S=14)
    gemm_sb3<false><<<dim3(16, 2, 14), 256, 0, stream>>>(
        flat_hi, flat_lo, Wv_w, nullptr, wpart, 12544, 12544, 256,
        (size_t)2048 * 256, 896);

    // K4: reduce + lnv + relu + residual + lnf
    k4_final<<<512, 256, 0, stream>>>(wpart, x, Wv_b, lnvg, lnvb, lnfg, lnfb, out);
}

// Round 8
// 892.969 us; speedup vs baseline: 1.2962x; 1.0898x over previous
//
#include <hip/hip_runtime.h>

#define LN_EPS 1e-5f

// Problem constants: N=2048, DIM_IN=256, DIM_V=256, VH=VW=7 (NK=49), H=64
//
// Pipeline:
//   k0_split : x -> xs_hi/xs_lo bf16 planes (trunc split)
//   gemm_sb3 : q[2048][32768] = x @ Wq^T + b   (split-bf16 3-term MFMA)
//   k2       : per-sample dynamic conv (fp32, 1024 thr) -> flat hi/lo bf16 planes
//   gemm_sb3 : wpart[14][2048][256] = flat @ Wv^T partials (split-K=14)
//   k4       : reduce 14 partials + bias -> lnv+relu -> +x -> lnf -> out
//
// ws layout (byte offsets), total 371,195,904:
//   [0, 268435456)          q fp32 [2048][32768]; reused as wpart after K2
//   [268435456, 371195904)  flat planes: hi ushort[2048][12544] @ +0,
//                                        lo @ +51380224
//   xs planes (2 MB) overlay the flat region during K0/K1 (dead by K2).

typedef __attribute__((ext_vector_type(8))) short short8;
typedef __attribute__((ext_vector_type(16))) float f32x16;

// ---------------------------------------------------------------------------
// K0: fp32 -> bf16 hi/lo planes (truncation split: exact a = hi + lo + O(2^-16))
// ---------------------------------------------------------------------------
__global__ __launch_bounds__(256) void k0_split(
    const float* __restrict__ in, ushort* __restrict__ hi,
    ushort* __restrict__ lo, int n4)
{
    const int i = blockIdx.x * 256 + threadIdx.x;
    if (i >= n4) return;
    const float4 f = ((const float4*)in)[i];
    const uint ux = __float_as_uint(f.x), uy = __float_as_uint(f.y);
    const uint uz = __float_as_uint(f.z), uw = __float_as_uint(f.w);
    ushort4 h, l;
    h.x = (ushort)(ux >> 16); h.y = (ushort)(uy >> 16);
    h.z = (ushort)(uz >> 16); h.w = (ushort)(uw >> 16);
    l.x = (ushort)(__float_as_uint(f.x - __uint_as_float(ux & 0xffff0000u)) >> 16);
    l.y = (ushort)(__float_as_uint(f.y - __uint_as_float(uy & 0xffff0000u)) >> 16);
    l.z = (ushort)(__float_as_uint(f.z - __uint_as_float(uz & 0xffff0000u)) >> 16);
    l.w = (ushort)(__float_as_uint(f.w - __uint_as_float(uw & 0xffff0000u)) >> 16);
    ((ushort4*)hi)[i] = h;
    ((ushort4*)lo)[i] = l;
}

// ---------------------------------------------------------------------------
// Split-bf16 3-term MFMA GEMM (unchanged — verified passing in round 6)
// ---------------------------------------------------------------------------
template<bool HAS_BIAS>
__global__ __launch_bounds__(256, 2) void gemm_sb3(
    const ushort* __restrict__ Ah, const ushort* __restrict__ Al,
    const float* __restrict__ B, const float* __restrict__ bias,
    float* __restrict__ C, int lda, int ldb, int ldc,
    size_t cSplitStride, int kPerSplit)
{
    __shared__ __align__(16) ushort sAh[8192];
    __shared__ __align__(16) ushort sAl[8192];
    __shared__ __align__(16) ushort sBh[8192];
    __shared__ __align__(16) ushort sBl[8192];

    const int tid = threadIdx.x;
    const int m0 = blockIdx.x << 7;
    const int j0 = blockIdx.y << 7;
    const int ks0 = blockIdx.z * kPerSplit;
    float* Cb = C + (size_t)blockIdx.z * cSplitStride;

    const int lane = tid & 63;
    const int wid = tid >> 6;
    const int wr = wid >> 1;
    const int wc = wid & 1;
    const int swz = (lane & 7) << 3;
    const int rA = (wr << 6) + (lane & 31);
    const int rB = (wc << 6) + (lane & 31);
    const int khalf = (lane >> 5) << 3;

    f32x16 acc[2][2];
#pragma unroll
    for (int r = 0; r < 2; ++r)
#pragma unroll
        for (int c = 0; c < 2; ++c)
#pragma unroll
            for (int e = 0; e < 16; ++e) acc[r][c][e] = 0.f;

    for (int kg0 = 0; kg0 < kPerSplit; kg0 += 64) {
        const int kg = ks0 + kg0;

        uint4 av[8];
#pragma unroll
        for (int p = 0; p < 2; ++p) {
            const ushort* src = p ? Al : Ah;
#pragma unroll
            for (int i = 0; i < 4; ++i) {
                const int id = tid + (i << 8);
                const int row = id >> 3;
                const int c8 = (id & 7) << 3;
                av[p * 4 + i] = *(const uint4*)(src + (size_t)(m0 + row) * lda + kg + c8);
            }
        }
        float4 bv[8];
#pragma unroll
        for (int i = 0; i < 8; ++i) {
            const int id = tid + (i << 8);
            const int row = id >> 4;
            const int c4 = (id & 15) << 2;
            bv[i] = *(const float4*)(B + (size_t)(j0 + row) * ldb + kg + c4);
        }

        if (kg0 > 0) __syncthreads();

#pragma unroll
        for (int p = 0; p < 2; ++p) {
            ushort* dst = p ? sAl : sAh;
#pragma unroll
            for (int i = 0; i < 4; ++i) {
                const int id = tid + (i << 8);
                const int row = id >> 3;
                const int c8 = (id & 7) << 3;
                *(uint4*)&dst[((row << 6) + c8) ^ ((row & 7) << 3)] = av[p * 4 + i];
            }
        }
#pragma unroll
        for (int i = 0; i < 8; ++i) {
            const int id = tid + (i << 8);
            const int row = id >> 4;
            const int c4 = (id & 15) << 2;
            const uint ux = __float_as_uint(bv[i].x), uy = __float_as_uint(bv[i].y);
            const uint uz = __float_as_uint(bv[i].z), uw = __float_as_uint(bv[i].w);
            const float lx = bv[i].x - __uint_as_float(ux & 0xffff0000u);
            const float ly = bv[i].y - __uint_as_float(uy & 0xffff0000u);
            const float lz = bv[i].z - __uint_as_float(uz & 0xffff0000u);
            const float lw = bv[i].w - __uint_as_float(uw & 0xffff0000u);
            const uint h01 = (ux >> 16) | (uy & 0xffff0000u);
            const uint h23 = (uz >> 16) | (uw & 0xffff0000u);
            const uint l01 = (__float_as_uint(lx) >> 16) | (__float_as_uint(ly) & 0xffff0000u);
            const uint l23 = (__float_as_uint(lz) >> 16) | (__float_as_uint(lw) & 0xffff0000u);
            const int sidx = ((row << 6) + c4) ^ ((row & 7) << 3);
            *(uint2*)&sBh[sidx] = make_uint2(h01, h23);
            *(uint2*)&sBl[sidx] = make_uint2(l01, l23);
        }
        __syncthreads();

#pragma unroll
        for (int ks = 0; ks < 4; ++ks) {
            const int kf = (ks << 4) + khalf;
            const int ia0 = ((rA << 6) + kf) ^ swz;
            const int ia1 = (((rA + 32) << 6) + kf) ^ swz;
            const int ib0 = ((rB << 6) + kf) ^ swz;
            const int ib1 = (((rB + 32) << 6) + kf) ^ swz;
            const short8 a0h = *(const short8*)&sAh[ia0];
            const short8 a0l = *(const short8*)&sAl[ia0];
            const short8 a1h = *(const short8*)&sAh[ia1];
            const short8 a1l = *(const short8*)&sAl[ia1];
            const short8 b0h = *(const short8*)&sBh[ib0];
            const short8 b0l = *(const short8*)&sBl[ib0];
            const short8 b1h = *(const short8*)&sBh[ib1];
            const short8 b1l = *(const short8*)&sBl[ib1];

            acc[0][0] = __builtin_amdgcn_mfma_f32_32x32x16_bf16(a0h, b0h, acc[0][0], 0, 0, 0);
            acc[0][1] = __builtin_amdgcn_mfma_f32_32x32x16_bf16(a0h, b1h, acc[0][1], 0, 0, 0);
            acc[1][0] = __builtin_amdgcn_mfma_f32_32x32x16_bf16(a1h, b0h, acc[1][0], 0, 0, 0);
            acc[1][1] = __builtin_amdgcn_mfma_f32_32x32x16_bf16(a1h, b1h, acc[1][1], 0, 0, 0);
            acc[0][0] = __builtin_amdgcn_mfma_f32_32x32x16_bf16(a0h, b0l, acc[0][0], 0, 0, 0);
            acc[0][1] = __builtin_amdgcn_mfma_f32_32x32x16_bf16(a0h, b1l, acc[0][1], 0, 0, 0);
            acc[1][0] = __builtin_amdgcn_mfma_f32_32x32x16_bf16(a1h, b0l, acc[1][0], 0, 0, 0);
            acc[1][1] = __builtin_amdgcn_mfma_f32_32x32x16_bf16(a1h, b1l, acc[1][1], 0, 0, 0);
            acc[0][0] = __builtin_amdgcn_mfma_f32_32x32x16_bf16(a0l, b0h, acc[0][0], 0, 0, 0);
            acc[0][1] = __builtin_amdgcn_mfma_f32_32x32x16_bf16(a0l, b1h, acc[0][1], 0, 0, 0);
            acc[1][0] = __builtin_amdgcn_mfma_f32_32x32x16_bf16(a1l, b0h, acc[1][0], 0, 0, 0);
            acc[1][1] = __builtin_amdgcn_mfma_f32_32x32x16_bf16(a1l, b1h, acc[1][1], 0, 0, 0);
        }
    }

#pragma unroll
    for (int rb = 0; rb < 2; ++rb)
#pragma unroll
        for (int cb = 0; cb < 2; ++cb) {
            const int col = j0 + (wc << 6) + (cb << 5) + (lane & 31);
            const float bvv = HAS_BIAS ? bias[col] : 0.0f;
            const int rbase = m0 + (wr << 6) + (rb << 5) + ((lane >> 5) << 2);
            float* cp = Cb + (size_t)rbase * ldc + col;
#pragma unroll
            for (int reg = 0; reg < 16; ++reg) {
                const int rr = (reg & 3) + ((reg >> 2) << 3);
                cp[(size_t)rr * ldc] = acc[rb][cb][reg] + bvv;
            }
        }
}

// ---------------------------------------------------------------------------
// K2: per-sample dynamic conv, 1024 threads (16 waves), 1 wg/sample.
//   - v staged linearly into [256 dv][52] (pad 49->52 keeps f4 align; magic-div)
//   - p2 prefetched into registers at start; written to LDS after phase A
//   - phase A: 208 thr, 4k x 4h, all-f4 LDS reads (conflict-free)
//   - LN0/LN1 fully in-register via shfl_xor butterflies (16/32-lane groups)
//   - phase B: 224 thr, 8k x 8j; LN1 -> hi/lo bf16 -> direct global write
// LDS: vL [256][52] (13312) | pL 16384 (p1 then p2) | tL [52][68] (3332)
// ---------------------------------------------------------------------------
__global__ __launch_bounds__(1024, 1) void k2_dynconv(
    const float* __restrict__ v, const float* __restrict__ q,
    const float* __restrict__ ln0g, const float* __restrict__ ln0b,
    const float* __restrict__ ln1g, const float* __restrict__ ln1b,
    ushort* __restrict__ fhi, ushort* __restrict__ flo)
{
    __shared__ __align__(16) float sm[33028];    // 132,112 B
    float* const vL = sm;                        // 13312
    float* const pL = sm + 13312;                // 16384
    float* const tL = sm + 29696;                // 3332

    const int n = blockIdx.x;
    const int tid = threadIdx.x;
    const float* vrow = v + (size_t)n * 12544;
    const float* qrow = q + (size_t)n * 32768;

    // ---- p2 prefetch into registers (latency hides under staging + phase A)
    float4 rp2[4];
#pragma unroll
    for (int j = 0; j < 4; ++j)
        rp2[j] = *(const float4*)(qrow + 16384 + ((tid + j * 1024) << 2));

    // ---- stage p1 (f4 linear)
#pragma unroll
    for (int j = 0; j < 4; ++j) {
        const int c = tid + j * 1024;
        *(float4*)&pL[c << 2] = *(const float4*)(qrow + (c << 2));
    }
    // ---- stage v: coalesced f4 load, re-stride 49->52 with magic-div by 49
#pragma unroll
    for (int j = 0; j < 4; ++j) {
        const int c = tid + j * 1024;
        if (c < 3136) {
            const float4 f = *(const float4*)(vrow + (c << 2));
            const int i0 = c << 2;
#pragma unroll
            for (int e = 0; e < 4; ++e) {
                const int i = i0 + e;
                const int dv = (int)(((uint)i * 85599u) >> 22);   // i/49, exact for i<89k
                const int k = i - dv * 49;
                vL[dv * 52 + k] = ((const float*)&f)[e];
            }
        }
    }
    __syncthreads();

    // ---- phase A: t1[49][64] = vt @ p1 ; 208 threads, 4k x 4h
    float ta[4][4];
    const int ktA = tid >> 4;              // k-tile (rows 4*ktA..+3)
    const int h0A = (tid & 15) << 2;
    if (tid < 208) {
#pragma unroll
        for (int r = 0; r < 4; ++r)
#pragma unroll
            for (int c = 0; c < 4; ++c) ta[r][c] = 0.f;
#pragma unroll 2
        for (int dv = 0; dv < 256; ++dv) {
            const float4 a4 = *(const float4*)&vL[dv * 52 + (ktA << 2)];
            const float4 b4 = *(const float4*)&pL[(dv << 6) + h0A];
            const float* ap = (const float*)&a4;
            const float* bp = (const float*)&b4;
#pragma unroll
            for (int r = 0; r < 4; ++r)
#pragma unroll
                for (int c = 0; c < 4; ++c)
                    ta[r][c] = fmaf(ap[r], bp[c], ta[r][c]);
        }
    }
    __syncthreads();   // phase A done reading p1/vL

    // ---- p2 regs -> LDS (all 1024 threads)
#pragma unroll
    for (int j = 0; j < 4; ++j)
        *(float4*)&pL[(tid + j * 1024) << 2] = rp2[j];

    // ---- LN0 + relu in-register (row k spread over 16 contiguous lanes)
    if (tid < 208) {
        float s1[4], s2[4];
#pragma unroll
        for (int r = 0; r < 4; ++r) {
            s1[r] = ta[r][0] + ta[r][1] + ta[r][2] + ta[r][3];
            s2[r] = ta[r][0]*ta[r][0] + ta[r][1]*ta[r][1]
                  + ta[r][2]*ta[r][2] + ta[r][3]*ta[r][3];
        }
#pragma unroll
        for (int m = 1; m < 16; m <<= 1)
#pragma unroll
            for (int r = 0; r < 4; ++r) {
                s1[r] += __shfl_xor(s1[r], m);
                s2[r] += __shfl_xor(s2[r], m);
            }
        const float4 g4 = *(const float4*)&ln0g[h0A];
        const float4 b4 = *(const float4*)&ln0b[h0A];
        const float* gp = (const float*)&g4;
        const float* bp = (const float*)&b4;
#pragma unroll
        for (int r = 0; r < 4; ++r) {
            const int k = (ktA << 2) + r;
            if (k < 49) {
                const float mean = s1[r] * (1.f / 64.f);
                const float var = s2[r] * (1.f / 64.f) - mean * mean;
                const float rstd = rsqrtf(var + LN_EPS);
                float4 o;
                o.x = fmaxf((ta[r][0] - mean) * rstd * gp[0] + bp[0], 0.f);
                o.y = fmaxf((ta[r][1] - mean) * rstd * gp[1] + bp[1], 0.f);
                o.z = fmaxf((ta[r][2] - mean) * rstd * gp[2] + bp[2], 0.f);
                o.w = fmaxf((ta[r][3] - mean) * rstd * gp[3] + bp[3], 0.f);
                *(float4*)&tL[k * 68 + h0A] = o;
            }
        }
    }
    __syncthreads();   // p2 staged + th ready

    // ---- phase B: t2[49][256] = th @ p2 ; 224 threads, 8k x 8j
    if (tid < 224) {
        const int kbB = tid >> 5;              // rows 8*kbB..+7 (clamped)
        const int j0B = (tid & 31) << 3;
        int roff[8];
#pragma unroll
        for (int r = 0; r < 8; ++r) {
            const int k = (kbB << 3) + r;
            roff[r] = (k < 49 ? k : 48) * 68;
        }
        float acc[8][8];
#pragma unroll
        for (int r = 0; r < 8; ++r)
#pragma unroll
            for (int c = 0; c < 8; ++c) acc[r][c] = 0.f;

        for (int hb = 0; hb < 16; ++hb) {      // 4 h per block
            float4 a4[8];
#pragma unroll
            for (int r = 0; r < 8; ++r)
                a4[r] = *(const float4*)&tL[roff[r] + (hb << 2)];
#pragma unroll
            for (int hh = 0; hh < 4; ++hh) {
                const int h = (hb << 2) + hh;
                const float4 b0 = *(const float4*)&pL[(h << 8) + j0B];
                const float4 b1 = *(const float4*)&pL[(h << 8) + j0B + 4];
                const float* bp0 = (const float*)&b0;
                const float* bp1 = (const float*)&b1;
#pragma unroll
                for (int r = 0; r < 8; ++r) {
                    const float a = ((const float*)&a4[r])[hh];
#pragma unroll
                    for (int c = 0; c < 4; ++c) {
                        acc[r][c]     = fmaf(a, bp0[c], acc[r][c]);
                        acc[r][c + 4] = fmaf(a, bp1[c], acc[r][c + 4]);
                    }
                }
            }
        }

        // ---- LN1 + relu in-register (row spread over 32 contiguous lanes)
        float s1[8], s2[8];
#pragma unroll
        for (int r = 0; r < 8; ++r) {
            float a1 = 0.f, a2 = 0.f;
#pragma unroll
            for (int c = 0; c < 8; ++c) { a1 += acc[r][c]; a2 += acc[r][c] * acc[r][c]; }
            s1[r] = a1; s2[r] = a2;
        }
#pragma unroll
        for (int m = 1; m < 32; m <<= 1)
#pragma unroll
            for (int r = 0; r < 8; ++r) {
                s1[r] += __shfl_xor(s1[r], m);
                s2[r] += __shfl_xor(s2[r], m);
            }
        const float4 g0 = *(const float4*)&ln1g[j0B];
        const float4 g1 = *(const float4*)&ln1g[j0B + 4];
        const float4 bb0 = *(const float4*)&ln1b[j0B];
        const float4 bb1 = *(const float4*)&ln1b[j0B + 4];
        const float* gp = (const float*)&g0;
        const float* gq = (const float*)&g1;
        const float* bp = (const float*)&bb0;
        const float* bq = (const float*)&bb1;
#pragma unroll
        for (int r = 0; r < 8; ++r) {
            const int k = (kbB << 3) + r;
            if (k < 49) {
                const float mean = s1[r] * (1.f / 256.f);
                const float var = s2[r] * (1.f / 256.f) - mean * mean;
                const float rstd = rsqrtf(var + LN_EPS);
                float o[8];
#pragma unroll
                for (int c = 0; c < 4; ++c) {
                    o[c]     = fmaxf((acc[r][c]     - mean) * rstd * gp[c] + bp[c], 0.f);
                    o[c + 4] = fmaxf((acc[r][c + 4] - mean) * rstd * gq[c] + bq[c], 0.f);
                }
                ushort4 h4a, h4b, l4a, l4b;
#pragma unroll
                for (int c = 0; c < 4; ++c) {
                    const uint u = __float_as_uint(o[c]);
                    ((ushort*)&h4a)[c] = (ushort)(u >> 16);
                    ((ushort*)&l4a)[c] = (ushort)(__float_as_uint(o[c] - __uint_as_float(u & 0xffff0000u)) >> 16);
                    const uint u2 = __float_as_uint(o[c + 4]);
                    ((ushort*)&h4b)[c] = (ushort)(u2 >> 16);
                    ((ushort*)&l4b)[c] = (ushort)(__float_as_uint(o[c + 4] - __uint_as_float(u2 & 0xffff0000u)) >> 16);
                }
                const size_t fo = (size_t)n * 12544 + k * 256 + j0B;
                *(ushort4*)&fhi[fo] = h4a;
                *(ushort4*)&fhi[fo + 4] = h4b;
                *(ushort4*)&flo[fo] = l4a;
                *(ushort4*)&flo[fo + 4] = l4b;
            }
        }
    }
}

// ---------------------------------------------------------------------------
// K4: reduce 14 split-K partials + Wv_b -> lnv+relu -> +x -> lnf -> out.
// ---------------------------------------------------------------------------
__global__ __launch_bounds__(256) void k4_final(
    const float* __restrict__ wpart, const float* __restrict__ x,
    const float* __restrict__ Wvb,
    const float* __restrict__ lnvg, const float* __restrict__ lnvb,
    const float* __restrict__ lnfg, const float* __restrict__ lnfb,
    float* __restrict__ out)
{
    const int n = (blockIdx.x << 2) + (threadIdx.x >> 6);
    const int lane = threadIdx.x & 63;
    const int j = lane << 2;

    float a0 = 0.f, a1 = 0.f, a2 = 0.f, a3 = 0.f;
#pragma unroll
    for (int s = 0; s < 14; ++s) {
        const float4 p = *(const float4*)&wpart[((size_t)s * 2048 + n) * 256 + j];
        a0 += p.x; a1 += p.y; a2 += p.z; a3 += p.w;
    }
    const float4 bb = *(const float4*)&Wvb[j];
    a0 += bb.x; a1 += bb.y; a2 += bb.z; a3 += bb.w;

    float s1 = a0 + a1 + a2 + a3;
    float s2 = a0*a0 + a1*a1 + a2*a2 + a3*a3;
#pragma unroll
    for (int off = 32; off > 0; off >>= 1) {
        s1 += __shfl_xor(s1, off);
        s2 += __shfl_xor(s2, off);
    }
    float m = s1 * (1.f / 256.f);
    float var = s2 * (1.f / 256.f) - m * m;
    float rr = rsqrtf(var + LN_EPS);
    const float4 g = *(const float4*)&lnvg[j];
    const float4 b = *(const float4*)&lnvb[j];
    const float w0 = fmaxf((a0 - m) * rr * g.x + b.x, 0.f);
    const float w1 = fmaxf((a1 - m) * rr * g.y + b.y, 0.f);
    const float w2 = fmaxf((a2 - m) * rr * g.z + b.z, 0.f);
    const float w3 = fmaxf((a3 - m) * rr * g.w + b.w, 0.f);

    const float4 xv = *(const float4*)&x[(size_t)n * 256 + j];
    const float t0 = xv.x + w0, t1 = xv.y + w1, t2 = xv.z + w2, t3 = xv.w + w3;
    s1 = t0 + t1 + t2 + t3;
    s2 = t0*t0 + t1*t1 + t2*t2 + t3*t3;
#pragma unroll
    for (int off = 32; off > 0; off >>= 1) {
        s1 += __shfl_xor(s1, off);
        s2 += __shfl_xor(s2, off);
    }
    m = s1 * (1.f / 256.f);
    var = s2 * (1.f / 256.f) - m * m;
    rr = rsqrtf(var + LN_EPS);
    const float4 gf = *(const float4*)&lnfg[j];
    const float4 bf = *(const float4*)&lnfb[j];
    float4 o;
    o.x = (t0 - m) * rr * gf.x + bf.x;
    o.y = (t1 - m) * rr * gf.y + bf.y;
    o.z = (t2 - m) * rr * gf.z + bf.z;
    o.w = (t3 - m) * rr * gf.w + bf.w;
    *(float4*)&out[(size_t)n * 256 + j] = o;
}

// ---------------------------------------------------------------------------
extern "C" void kernel_launch(void* const* d_in, const int* in_sizes, int n_in,
                              void* d_out, int out_size, void* d_ws, size_t ws_size,
                              hipStream_t stream)
{
    const float* x    = (const float*)d_in[0];
    const float* v    = (const float*)d_in[1];
    const float* Wq_w = (const float*)d_in[2];
    const float* Wq_b = (const float*)d_in[3];
    const float* ln0g = (const float*)d_in[4];
    const float* ln0b = (const float*)d_in[5];
    const float* ln1g = (const float*)d_in[6];
    const float* ln1b = (const float*)d_in[7];
    const float* Wv_w = (const float*)d_in[8];
    const float* Wv_b = (const float*)d_in[9];
    const float* lnvg = (const float*)d_in[10];
    const float* lnvb = (const float*)d_in[11];
    const float* lnfg = (const float*)d_in[12];
    const float* lnfb = (const float*)d_in[13];
    float* out = (float*)d_out;

    if (ws_size < 371195904ull) return;  // loud failure: out stays poisoned
    char* ws = (char*)d_ws;
    float* q        = (float*)ws;                          // [2048][32768] fp32
    ushort* flat_hi = (ushort*)(ws + 268435456u);          // [2048][12544] bf16
    ushort* flat_lo = (ushort*)(ws + 319815680u);
    ushort* xs_hi   = (ushort*)(ws + 268435456u);          // overlay (dead by K2)
    ushort* xs_lo   = xs_hi + 524288;
    float* wpart    = q;                                   // [14][2048][256] fp32

    k0_split<<<512, 256, 0, stream>>>(x, xs_hi, xs_lo, 131072);

    gemm_sb3<true><<<dim3(16, 256, 1), 256, 0, stream>>>(
        xs_hi, xs_lo, Wq_w, Wq_b, q, 256, 256, 32768, 0, 256);

    k2_dynconv<<<2048, 1024, 0, stream>>>(v, q, ln0g, ln0b, ln1g, ln1b,
                                          flat_hi, flat_lo);

    gemm_sb3<false><<<dim3(16, 2, 14), 256, 0, stream>>>(
        flat_hi, flat_lo, Wv_w, nullptr, wpart, 12544, 12544, 256,
        (size_t)2048 * 256, 896);

    k4_final<<<512, 256, 0, stream>>>(wpart, x, Wv_b, lnvg, lnvb, lnfg, lnfb, out);
}